// Round 2
// baseline (398.846 us; speedup 1.0000x reference)
//
#include <hip/hip_runtime.h>
#include <stdint.h>

typedef __bf16          bf16x8  __attribute__((ext_vector_type(8)));
typedef unsigned short  ushort8 __attribute__((ext_vector_type(8)));
typedef float           f32x4   __attribute__((ext_vector_type(4)));

__device__ __forceinline__ unsigned short f2bf(float f) {
    unsigned int u = __float_as_uint(f);
    return (unsigned short)((u + 0x7FFFu + ((u >> 16) & 1u)) >> 16);
}

#define W1_SLOTS (12*16*64)
#define W2_SLOTS (8*16*64)

// Repack w1 (384x256) / w2 (256x256) row-major fp32 -> bf16 in MFMA B-fragment
// order: slot (s,t,l) holds w[k = s*32 + (l>>4)*8 + j][n = t*16 + (l&15)], j=0..7.
__global__ void prep_weights(const float* __restrict__ w1, const float* __restrict__ w2,
                             unsigned short* __restrict__ w1f, unsigned short* __restrict__ w2f) {
    int id = blockIdx.x * 256 + threadIdx.x;
    const float* src; unsigned short* dst; int slot;
    if (id < W1_SLOTS)                { src = w1; dst = w1f; slot = id; }
    else if (id < W1_SLOTS + W2_SLOTS){ src = w2; dst = w2f; slot = id - W1_SLOTS; }
    else return;
    int l  = slot & 63;
    int t  = (slot >> 6) & 15;
    int s  = slot >> 10;
    int k0 = s*32 + ((l >> 4) << 3);
    int n  = t*16 + (l & 15);
    unsigned short* d = dst + (size_t)slot * 8;
    #pragma unroll
    for (int j = 0; j < 8; ++j) d[j] = f2bf(src[(size_t)(k0 + j) * 256 + n]);
}

// Block: 256 threads, 128 rows. Wave wv owns output cols [64*wv, 64*wv+64) for
// BOTH layers (4 n-tiles), all 8 m-tiles. B-frags straight from global (L2-hot).
// Embeddings filled once per 192-k half into LDS (A-frag order, XOR-swizzled);
// the same 64 KB LDS region is reused for h1 between the layers.
// Barriers per block: 5 (vs 40 in round 1).
__global__ __launch_bounds__(256, 2) void courier_main(
    const float* __restrict__ xy,   const float* __restrict__ tin,
    const float* __restrict__ w_sx, const float* __restrict__ b_sx,
    const float* __restrict__ w_cx, const float* __restrict__ b_cx,
    const float* __restrict__ w_sy, const float* __restrict__ b_sy,
    const float* __restrict__ w_cy, const float* __restrict__ b_cy,
    const float* __restrict__ w_t,  const float* __restrict__ b_t,
    const unsigned short* __restrict__ w1f, const float* __restrict__ b1,
    const unsigned short* __restrict__ w2f, const float* __restrict__ b2,
    float* __restrict__ out)
{
    __shared__ __align__(16) unsigned short smem[128*256];   // 64 KB union: embed(48K) / h1(64K)

    const int tid  = threadIdx.x;
    const int lane = tid & 63;
    const int wv   = tid >> 6;          // wave 0..3: owns cols [64wv, 64wv+64)
    const int l15  = lane & 15;
    const int lq   = lane >> 4;
    const int rowblk = blockIdx.x * 128;

    // --- per-thread embed-fill row (fixed): threads 0-127 do even granules, 128-255 odd
    const int er    = tid & 127;
    const int gpar  = tid >> 7;         // 0 or 1
    const float ex = xy[(size_t)(rowblk + er)*2 + 0];
    const float ey = xy[(size_t)(rowblk + er)*2 + 1];
    const float et = tin[rowblk + er];

    f32x4 acc[8][4];
    #pragma unroll
    for (int m=0;m<8;++m)
      #pragma unroll
      for (int n=0;n<4;++n)
        #pragma unroll
        for (int i=0;i<4;++i) acc[m][n][i] = 0.0f;

    const bf16x8* w1v = (const bf16x8*)w1f;
    const bf16x8* w2v = (const bf16x8*)w2f;

    // ================= layer 1: two 192-k halves =================
    #pragma unroll
    for (int half = 0; half < 2; ++half) {
        if (half) __syncthreads();      // waves done reading previous embed half

        // ---- fill embed LDS: value(row er, k) in A-frag granule order, swizzled
        // granule g in [0,24): local k = g*8+j, global k = half*192 + g*8 + j
        #pragma unroll
        for (int it = 0; it < 12; ++it) {
            const int g  = gpar + it*2;
            const int kg = half*192 + g*8;
            const int seg = kg >> 6;             // wave-uniform
            const float* wp; const float* bp; float cc; int mode;
            if      (seg == 0) { wp = w_sx; bp = b_sx; cc = ex; mode = 0; }
            else if (seg == 1) { wp = w_cx; bp = b_cx; cc = ex; mode = 1; }
            else if (seg == 2) { wp = w_sy; bp = b_sy; cc = ey; mode = 0; }
            else if (seg == 3) { wp = w_cy; bp = b_cy; cc = ey; mode = 1; }
            else               { wp = w_t;  bp = b_t;  cc = et; mode = 2; }
            const int o = (seg < 4) ? (kg & 63) : (kg - 256);
            f32x4 wa = *(const f32x4*)(wp+o), wb = *(const f32x4*)(wp+o+4);
            f32x4 ba = *(const f32x4*)(bp+o), bb = *(const f32x4*)(bp+o+4);
            ushort8 u;
            #pragma unroll
            for (int j = 0; j < 8; ++j) {
                float wvv = (j<4)?wa[j]:wb[j-4];
                float bvv = (j<4)?ba[j]:bb[j-4];
                float th = cc*wvv + bvv;
                float v;
                if      (mode == 0) v = __sinf(th);
                else if (mode == 1) v = __cosf(th);
                else                v = fmaxf(th, 0.01f*th);
                u[j] = f2bf(v);
            }
            *(ushort8*)&smem[er*192 + ((g ^ (er & 7)) << 3)] = u;
        }
        __syncthreads();

        // ---- 6 k-steps, no barriers inside
        #pragma unroll
        for (int s = 0; s < 6; ++s) {
            const int sg = half*6 + s;
            bf16x8 bfr[4];
            #pragma unroll
            for (int n = 0; n < 4; ++n)
                bfr[n] = w1v[(sg*16 + wv*4 + n)*64 + lane];
            bf16x8 afr[8];
            #pragma unroll
            for (int m = 0; m < 8; ++m) {
                const int row = m*16 + l15;
                afr[m] = *(const bf16x8*)&smem[row*192 + (((s*4 + lq) ^ (l15 & 7)) << 3)];
            }
            #pragma unroll
            for (int m = 0; m < 8; ++m)
              #pragma unroll
              for (int n = 0; n < 4; ++n)
                acc[m][n] = __builtin_amdgcn_mfma_f32_16x16x32_bf16(afr[m], bfr[n], acc[m][n], 0,0,0);
        }
    }
    __syncthreads();   // all waves done reading embed before h1 overwrites region

    // ================= epilogue 1: h1 = leaky(acc+b1) -> LDS bf16, A-order swizzled
    #pragma unroll
    for (int n = 0; n < 4; ++n) {
        const int c  = wv*64 + n*16 + l15;
        const float bv = b1[c];
        const int g  = c >> 3;
        #pragma unroll
        for (int m = 0; m < 8; ++m) {
            #pragma unroll
            for (int rg = 0; rg < 4; ++rg) {
                const int row = m*16 + lq*4 + rg;
                float v = acc[m][n][rg] + bv;
                v = fmaxf(v, 0.01f*v);
                smem[row*256 + ((g ^ (row & 7)) << 3) + (c & 7)] = f2bf(v);
            }
        }
    }
    #pragma unroll
    for (int m=0;m<8;++m)
      #pragma unroll
      for (int n=0;n<4;++n)
        #pragma unroll
        for (int i=0;i<4;++i) acc[m][n][i] = 0.0f;
    __syncthreads();

    // ================= layer 2: 8 k-steps, no barriers inside =================
    #pragma unroll
    for (int s2 = 0; s2 < 8; ++s2) {
        bf16x8 bfr[4];
        #pragma unroll
        for (int n = 0; n < 4; ++n)
            bfr[n] = w2v[(s2*16 + wv*4 + n)*64 + lane];
        bf16x8 afr[8];
        #pragma unroll
        for (int m = 0; m < 8; ++m) {
            const int row = m*16 + l15;
            afr[m] = *(const bf16x8*)&smem[row*256 + (((s2*4 + lq) ^ (l15 & 7)) << 3)];
        }
        #pragma unroll
        for (int m = 0; m < 8; ++m)
          #pragma unroll
          for (int n = 0; n < 4; ++n)
            acc[m][n] = __builtin_amdgcn_mfma_f32_16x16x32_bf16(afr[m], bfr[n], acc[m][n], 0,0,0);
    }

    // ================= epilogue 2: out = leaky(acc+b2), fp32 =================
    #pragma unroll
    for (int n = 0; n < 4; ++n) {
        const int c  = wv*64 + n*16 + l15;
        const float bv = b2[c];
        #pragma unroll
        for (int m = 0; m < 8; ++m) {
            #pragma unroll
            for (int rg = 0; rg < 4; ++rg) {
                const int row = rowblk + m*16 + lq*4 + rg;
                float v = acc[m][n][rg] + bv;
                v = fmaxf(v, 0.01f*v);
                out[(size_t)row*256 + c] = v;
            }
        }
    }
}

extern "C" void kernel_launch(void* const* d_in, const int* in_sizes, int n_in,
                              void* d_out, int out_size, void* d_ws, size_t ws_size,
                              hipStream_t stream) {
    const float* xy   = (const float*)d_in[0];
    const float* tin  = (const float*)d_in[1];
    const float* w_sx = (const float*)d_in[2];
    const float* b_sx = (const float*)d_in[3];
    const float* w_cx = (const float*)d_in[4];
    const float* b_cx = (const float*)d_in[5];
    const float* w_sy = (const float*)d_in[6];
    const float* b_sy = (const float*)d_in[7];
    const float* w_cy = (const float*)d_in[8];
    const float* b_cy = (const float*)d_in[9];
    const float* w_t  = (const float*)d_in[10];
    const float* b_t  = (const float*)d_in[11];
    const float* w1   = (const float*)d_in[12];
    const float* b1   = (const float*)d_in[13];
    const float* w2   = (const float*)d_in[14];
    const float* b2   = (const float*)d_in[15];

    unsigned short* w1f = (unsigned short*)d_ws;        // 196608 B
    unsigned short* w2f = w1f + (size_t)W1_SLOTS * 8;   // 131072 B

    prep_weights<<<(W1_SLOTS + W2_SLOTS + 255)/256, 256, 0, stream>>>(w1, w2, w1f, w2f);
    courier_main<<<262144/128, 256, 0, stream>>>(xy, tin, w_sx,b_sx,w_cx,b_cx,
                                                 w_sy,b_sy,w_cy,b_cy,w_t,b_t,
                                                 w1f, b1, w2f, b2, (float*)d_out);
}